// Round 1
// baseline (93.257 us; speedup 1.0000x reference)
//
#include <hip/hip_runtime.h>

// MinibatchDiscrimination: B=512, IN=512, OUT=64, KD=8 (fp32 in/out)
// out[i, 0:512] = x[i, :]
// out[i, 512+o] = sum_j exp(-sum_k |M[i,o,k] - M[j,o,k]|),  M = x @ T
//
// R5: SINGLE fused kernel, ZERO workspace use.
//  Rationale: rocprof shows a 256 MiB / 40 us fillBufferAligned (harness ws
//  re-poison) dominating the 71 us iteration; our two kernels model out at
//  ~12-15 us. Fusing removes the inter-kernel launch gap + Mt round-trip and
//  drops d_ws entirely (tests whether the poison fill follows ws usage).
//
//  Grid 256 = (o=64) x (ic=4), 512 thr = 8 waves, 1 block/CU.
//  Phase 1: block recomputes its own o-slice M[:,o,:] (512x8) via MFMA.
//    - T[:,o,:]^T staged to LDS as bf16 once (btT[kd][k], pad 520).
//    - B-frags for all 16 k-steps preloaded to 64 VGPRs (shared across the
//      4 j-tiles per wave); only cols 0..7 real, cols 8..15 duplicate (r&7)
//      and their C columns are never stored. MFMA is ~0.3 us chip-wide.
//    - A-frags: x rows read fp32 from global (L2-resident; 1 MB/block is the
//      redundancy price: 256 MB L2 ~ 7.4 us chip-wide), packed to bf16 in-reg.
//    - M rows stored to LDS s[j][SROW=12] (48 B stride: 16B-aligned for b128,
//      8-way instead of 16-way bank aliasing on the per-lane mi reads).
//  Phase 2: identical structure to R4's pairs kernel, reading s from LDS.
//    wave w owns j-window [w*64,w*64+64), 2 i/thread, wave-uniform sj reads
//    broadcast, s2 cross-wave reduce, exclusive final store. x->out copy
//    folded in (issued before first barrier, hides under phase 1).

#define B_    512
#define IN_   512
#define OUT_  64
#define KD_   8
#define ROW_  576
#define ROW4_ 144
#define SROW  12   // padded M-row stride in floats (48 B)

typedef short short8 __attribute__((ext_vector_type(8)));
typedef float f32x4  __attribute__((ext_vector_type(4)));

__device__ __forceinline__ unsigned short f2bf(float f) {
    // round-half-up truncation to bf16; exp(-d) suppression makes the
    // 0.4% relative error invisible (non-self d ~ 200, self-term exact 0)
    return (unsigned short)((__float_as_uint(f) + 0x8000u) >> 16);
}
__device__ __forceinline__ unsigned pack_bf2(float lo, float hi) {
    unsigned a = (__float_as_uint(lo) + 0x8000u) >> 16;
    unsigned b = (__float_as_uint(hi) + 0x8000u) & 0xFFFF0000u;
    return a | b;
}

__global__ __launch_bounds__(512)
void fused_kernel(const float* __restrict__ x, const float* __restrict__ T,
                  float* __restrict__ out) {
    __shared__ __attribute__((aligned(16))) float s[B_ * SROW];         // 24 KB M-slice
    __shared__ __attribute__((aligned(16))) unsigned short btT[8][520]; // 8.1 KB T^T bf16
    __shared__ __attribute__((aligned(16))) float s2[8][128];           // 4 KB partials

    int t  = threadIdx.x;
    int bx = blockIdx.x;
    int o  = bx >> 2;
    int ic = bx & 3;

    // side job: copy this block's 4 KB share of x into out cols 0..511
    // (issued before the first barrier; hides under phase-1 loads)
    if (t < 256) {
        int v = bx * 256 + t;                 // [0, 65536) float4s of x
        ((float4*)out)[(v >> 7) * ROW4_ + (v & 127)] = ((const float4*)x)[v];
    }

    // stage T[:,o,:]^T as bf16: btT[kd][k], thread t handles k = t
    {
        const float* tp = T + t * (OUT_ * KD_) + o * KD_;
        float4 a = *(const float4*)tp;
        float4 b = *(const float4*)(tp + 4);
        btT[0][t] = f2bf(a.x); btT[1][t] = f2bf(a.y);
        btT[2][t] = f2bf(a.z); btT[3][t] = f2bf(a.w);
        btT[4][t] = f2bf(b.x); btT[5][t] = f2bf(b.y);
        btT[6][t] = f2bf(b.z); btT[7][t] = f2bf(b.w);
    }
    __syncthreads();

    int lane = t & 63, w = t >> 6;
    int r = lane & 15, q = lane >> 4;

    // ---- phase 1: wave w computes M rows [w*64, w*64+64) ----------------
    // preload all 16 B-fragments once (reused across the 4 j-tiles)
    short8 Bv[16];
    {
        int rb = r & 7;                       // lanes r>=8 duplicate cols 0..7;
        #pragma unroll                        // their C columns are never stored
        for (int kt = 0; kt < 16; ++kt)
            Bv[kt] = *(const short8*)&btT[rb][q * 8 + kt * 32];
    }
    #pragma unroll
    for (int tt = 0; tt < 4; ++tt) {
        int j0 = w * 64 + tt * 16;
        const float* pa = x + (j0 + r) * IN_ + q * 8;
        f32x4 acc = {0.f, 0.f, 0.f, 0.f};
        #pragma unroll
        for (int kt = 0; kt < 16; ++kt) {
            float4 f0 = *(const float4*)(pa + kt * 32);
            float4 f1 = *(const float4*)(pa + kt * 32 + 4);
            union { unsigned u[4]; short8 v; } A;
            A.u[0] = pack_bf2(f0.x, f0.y);
            A.u[1] = pack_bf2(f0.z, f0.w);
            A.u[2] = pack_bf2(f1.x, f1.y);
            A.u[3] = pack_bf2(f1.z, f1.w);
            acc = __builtin_amdgcn_mfma_f32_16x16x32_bf16(A.v, Bv[kt], acc, 0, 0, 0);
        }
        // C/D map: row = q*4+rr, col = r  ->  j = j0+q*4+rr, kd = r (<8 real)
        if (r < 8) {
            #pragma unroll
            for (int rr = 0; rr < 4; ++rr)
                s[(j0 + q * 4 + rr) * SROW + r] = acc[rr];
        }
    }
    __syncthreads();

    // ---- phase 2: all-pairs L1 + exp ------------------------------------
    float mi[2][KD_];
    #pragma unroll
    for (int ii = 0; ii < 2; ++ii) {
        const float* p = s + (ic * 128 + lane + ii * 64) * SROW;
        float4 lo = *(const float4*)p;
        float4 hi = *(const float4*)(p + 4);
        mi[ii][0] = lo.x; mi[ii][1] = lo.y; mi[ii][2] = lo.z; mi[ii][3] = lo.w;
        mi[ii][4] = hi.x; mi[ii][5] = hi.y; mi[ii][6] = hi.z; mi[ii][7] = hi.w;
    }

    float acc0 = 0.f, acc1 = 0.f;
    const float* sj = s + w * 64 * SROW;     // wave-uniform -> LDS broadcast
    #pragma unroll 4
    for (int jj = 0; jj < 64; ++jj) {
        float4 vlo = *(const float4*)sj;
        float4 vhi = *(const float4*)(sj + 4);
        sj += SROW;
        float d0 = fabsf(mi[0][0] - vlo.x) + fabsf(mi[0][1] - vlo.y)
                 + fabsf(mi[0][2] - vlo.z) + fabsf(mi[0][3] - vlo.w)
                 + fabsf(mi[0][4] - vhi.x) + fabsf(mi[0][5] - vhi.y)
                 + fabsf(mi[0][6] - vhi.z) + fabsf(mi[0][7] - vhi.w);
        float d1 = fabsf(mi[1][0] - vlo.x) + fabsf(mi[1][1] - vlo.y)
                 + fabsf(mi[1][2] - vlo.z) + fabsf(mi[1][3] - vlo.w)
                 + fabsf(mi[1][4] - vhi.x) + fabsf(mi[1][5] - vhi.y)
                 + fabsf(mi[1][6] - vhi.z) + fabsf(mi[1][7] - vhi.w);
        acc0 += __expf(-d0);
        acc1 += __expf(-d1);
    }
    s2[w][lane]      = acc0;
    s2[w][lane + 64] = acc1;
    __syncthreads();

    // exclusive final store: this block owns (o, i) for i in [ic*128, +128)
    if (t < 128) {
        float v = 0.f;
        #pragma unroll
        for (int ww = 0; ww < 8; ++ww) v += s2[ww][t];
        out[(ic * 128 + t) * ROW_ + IN_ + o] = v;
    }
}

extern "C" void kernel_launch(void* const* d_in, const int* in_sizes, int n_in,
                              void* d_out, int out_size, void* d_ws, size_t ws_size,
                              hipStream_t stream) {
    const float* x = (const float*)d_in[0];   // [512, 512]
    const float* T = (const float*)d_in[1];   // [512, 64, 8]
    float* out = (float*)d_out;               // [512, 576]
    (void)d_ws; (void)ws_size;                // workspace deliberately unused

    fused_kernel<<<256, 512, 0, stream>>>(x, T, out);
}

// Round 3
// 72.971 us; speedup vs baseline: 1.2780x; 1.2780x over previous
//
#include <hip/hip_runtime.h>

// MinibatchDiscrimination: B=512, IN=512, OUT=64, KD=8 (fp32 in/out)
// out[i, 0:512] = x[i, :]
// out[i, 512+o] = sum_j exp(-sum_k |M[i,o,k] - M[j,o,k]|),  M = x @ T
//
// R7 = R6 with the K2 LDS-stage bug fixed (p<16 -> p<4; R6 wrote ~98KB past
// a 24KB LDS array -> GPU fault -> "container failed twice").
//
// Structure (rationale in R5/R6 notes):
//  - 256MiB ws poison fill (~40us) is UNCONDITIONAL -> d_ws is free to use.
//  - Floor = 40us fill + ~10us gaps + kernel time; attack kernel time w/ TLP.
//  K1 gemm : grid 256 x 512thr (8 waves = 2/SIMD). 64x16 tile; K=512 split
//            across wave pairs (waves 0-3: k<256, 4-7: k>=256), LDS reduce.
//            Stores Mt PRE-SCALED by log2(e) so K2 uses raw exp2.
//  K2 pairs: grid 1024 = (o=64) x (ic=16 i-chunks of 32), 256 thr ->
//            4 blocks/CU = 4 waves/SIMD (2x R4's TLP).
//            Thread = 1 i x 64-j window (8 windows). Full 16KB o-slice in
//            LDS (SROW=12 pad, 4 float4/thread stage). sj reads: 2 bcast
//            addrs/wave (free). mi read from GLOBAL concurrently with the
//            stage. Inner iter: 8 sub + 8 |.|+add + exp2 + acc ~ 18 VALU.
//            x->out copy folded in (64 float4/block).

#define B_    512
#define IN_   512
#define OUT_  64
#define KD_   8
#define ROW_  576
#define ROW4_ 144
#define SROW  12           // padded M-row stride in floats (48 B, 16B-aligned)
#define LOG2E 1.44269504088896340736f

typedef short short8 __attribute__((ext_vector_type(8)));
typedef float f32x4  __attribute__((ext_vector_type(4)));

__device__ __forceinline__ unsigned short f2bf(float f) {
    // round-half-up truncation to bf16; exp(-d) suppression makes the
    // 0.4% relative error invisible (non-self d ~ 200, self-term exact 0)
    return (unsigned short)((__float_as_uint(f) + 0x8000u) >> 16);
}
__device__ __forceinline__ unsigned pack_bf2(float lo, float hi) {
    unsigned a = (__float_as_uint(lo) + 0x8000u) >> 16;
    unsigned b = (__float_as_uint(hi) + 0x8000u) & 0xFFFF0000u;
    return a | b;
}

// ---------------- K1: fused transpose + GEMM (K-split, 8 waves) -------------
__global__ __launch_bounds__(512)
void gemm_kernel(const float* __restrict__ x, const float* __restrict__ T,
                 float* __restrict__ Mt) {
    __shared__ unsigned short ts[16][520];            // [n-local][k] bf16
    __shared__ __attribute__((aligned(16))) f32x4 sred[4][64];  // K-half partials
    int t  = threadIdx.x;
    int bx = blockIdx.x;
    int nb = bx & 31, ib = bx >> 5;
    int n0 = nb * 16;

    // stage T[k][n0+c] -> ts[c][k] as bf16 (transpose+convert), 16 k/thread
    {
        int c  = t & 15;
        int kb = t >> 4;                              // 0..31
        #pragma unroll
        for (int p = 0; p < 16; ++p) {
            int k = kb + p * 32;
            ts[c][k] = f2bf(T[k * 512 + n0 + c]);
        }
    }
    __syncthreads();

    int lane = t & 63, wid = t >> 6;                  // wid 0..7
    int r = lane & 15, q = lane >> 4;
    int wrow  = wid & 3;                              // which 16-row i-subtile
    int khalf = wid >> 2;                             // 0: k<256, 1: k>=256
    int i0 = ib * 64 + wrow * 16;
    const float* pa = x + (i0 + r) * 512 + q * 8 + khalf * 256;

    f32x4 acc = {0.f, 0.f, 0.f, 0.f};
    #pragma unroll
    for (int kt = 0; kt < 8; ++kt) {
        float4 f0 = *(const float4*)(pa + kt * 32);
        float4 f1 = *(const float4*)(pa + kt * 32 + 4);
        union { unsigned u[4]; short8 v; } A;
        A.u[0] = pack_bf2(f0.x, f0.y);
        A.u[1] = pack_bf2(f0.z, f0.w);
        A.u[2] = pack_bf2(f1.x, f1.y);
        A.u[3] = pack_bf2(f1.z, f1.w);
        short8 Bv = *(const short8*)&ts[r][q * 8 + khalf * 256 + kt * 32];
        acc = __builtin_amdgcn_mfma_f32_16x16x32_bf16(A.v, Bv, acc, 0, 0, 0);
    }

    if (khalf == 1) sred[wrow][lane] = acc;
    __syncthreads();
    if (khalf == 0) {
        f32x4 oth = sred[wrow][lane];
        // C/D map: row = q*4+rr, col = r -> i = i0+q*4+rr, oc = n0+r
        // store PRE-SCALED by log2e: K2 then uses exp2 directly
        int oc = n0 + r;
        float* dst = Mt + (oc >> 3) * (B_ * KD_) + (oc & 7);
        #pragma unroll
        for (int rr = 0; rr < 4; ++rr)
            dst[(i0 + q * 4 + rr) * KD_] = (acc[rr] + oth[rr]) * LOG2E;
    }
}

// ---------------- K2: all-pairs L1 + exp2 + x-copy --------------------------
__global__ __launch_bounds__(256)
void pairs_kernel(const float* __restrict__ Mt, const float* __restrict__ x,
                  float* __restrict__ out) {
    __shared__ __attribute__((aligned(16))) float s[B_ * SROW];  // 24 KB
    __shared__ float s2[8][33];                       // window partials (pad 33)
    int t  = threadIdx.x;
    int bx = blockIdx.x;
    int o  = bx >> 4;
    int ic = bx & 15;
    const float* base = Mt + o * (B_ * KD_);

    int il  = t & 31;                                 // i_local 0..31
    int win = t >> 5;                                 // j-window 0..7

    // mi straight from global (independent of the LDS stage -> overlaps)
    const float* pmi = base + (ic * 32 + il) * KD_;
    float4 mlo = *(const float4*)pmi;
    float4 mhi = *(const float4*)(pmi + 4);

    // stage the full 16KB slice into padded LDS:
    // 1024 float4s / 256 threads = 4 float4/thread  (R6 bug: had p<16)
    #pragma unroll
    for (int p = 0; p < 4; ++p) {
        int f = t + p * 256;                          // float4 idx 0..1023
        int j = f >> 1, h = f & 1;                    // j 0..511
        *(float4*)&s[j * SROW + h * 4] = ((const float4*)base)[f];
    }

    // side job: copy this block's 1KB share of x into out cols 0..511
    if (t < 64) {
        int v = bx * 64 + t;                          // [0, 65536) float4s
        ((float4*)out)[(v >> 7) * ROW4_ + (v & 127)] = ((const float4*)x)[v];
    }
    __syncthreads();

    float m0 = mlo.x, m1 = mlo.y, m2 = mlo.z, m3 = mlo.w;
    float m4 = mhi.x, m5 = mhi.y, m6 = mhi.z, m7 = mhi.w;

    float acc = 0.f;
    const float* sj = s + win * 64 * SROW;            // 2 bcast addrs / wave
    #pragma unroll 4
    for (int jj = 0; jj < 64; ++jj) {
        float4 vlo = *(const float4*)sj;
        float4 vhi = *(const float4*)(sj + 4);
        sj += SROW;
        float d = fabsf(m0 - vlo.x) + fabsf(m1 - vlo.y)
                + fabsf(m2 - vlo.z) + fabsf(m3 - vlo.w)
                + fabsf(m4 - vhi.x) + fabsf(m5 - vhi.y)
                + fabsf(m6 - vhi.z) + fabsf(m7 - vhi.w);
        acc += exp2f(-d);                             // Mt pre-scaled by log2e
    }
    s2[win][il] = acc;
    __syncthreads();

    // exclusive final store: this block owns (o, i) for i in [ic*32, +32)
    if (t < 32) {
        float v = 0.f;
        #pragma unroll
        for (int ww = 0; ww < 8; ++ww) v += s2[ww][t];
        out[(ic * 32 + t) * ROW_ + IN_ + o] = v;
    }
}

extern "C" void kernel_launch(void* const* d_in, const int* in_sizes, int n_in,
                              void* d_out, int out_size, void* d_ws, size_t ws_size,
                              hipStream_t stream) {
    const float* x = (const float*)d_in[0];   // [512, 512]
    const float* T = (const float*)d_in[1];   // [512, 64, 8]
    float* out = (float*)d_out;               // [512, 576]
    float* Mt  = (float*)d_ws;                // [64][512][8] fp32 (x log2e), 1 MB

    gemm_kernel<<<256, 512, 0, stream>>>(x, T, Mt);
    pairs_kernel<<<1024, 256, 0, stream>>>(Mt, x, out);
}